// Round 4
// baseline (202.759 us; speedup 1.0000x reference)
//
#include <hip/hip_runtime.h>
#include <hip/hip_fp16.h>
#include <math.h>

#define DD 96
#define VOX (96*96*96)
#define NB 8
#define NC 128
#define L3 125

// ---- blur tiling: 16^3 output tile, x->y->z in-place passes ----
#define BTS 16
#define BNT 6
#define BNTILE (BNT*BNT*BNT)   // 216
#define BHZ 22                 // z halo extent
#define BHY 22                 // y halo extent
// LDS layout: xs[(hy*23 + hz)*16 + xo]  (hz stride padded 22->23)
#define XSN (BHY * 23 * BTS)   // 8096 floats = 31.6 KB

// ---- sample tiling: (z,y,x) = (12,8,32), x-quads, 4 z-slices/iter ----
#define TZ 12
#define TY 8
#define TX 32
#define NTZ 8                  // 96/12
#define NTY 12                 // 96/8
#define NTX 3
#define STILE (NTZ*NTY*NTX)    // 288 (divisible by 8 -> XCD octants)

typedef float vfloat2 __attribute__((ext_vector_type(2)));
typedef float vfloat4 __attribute__((ext_vector_type(4)));
// 8-byte tap-pair load, only 4-byte aligned (x offset is arbitrary)
typedef float f2u __attribute__((ext_vector_type(2), aligned(4)));

// ---------------- 7^3 box blur (x->y->z, in-place LDS) + alpha tail -------
__global__ __launch_bounds__(256) void blur_alpha(
        const float* __restrict__ in, float* __restrict__ out,
        const float* __restrict__ enc,
        const float* __restrict__ c1_w, const float* __restrict__ c1_b,
        const float* __restrict__ f1_w, const float* __restrict__ f1_b,
        float* __restrict__ alpha) {
    __shared__ float xs[XSN];
    __shared__ float red[4];
    int tid = threadIdx.x;

    if (blockIdx.x >= 3 * BNTILE) {
        // -------- alpha path (8 blocks) --------
        int b = blockIdx.x - 3 * BNTILE;
        const float4* e4 = (const float4*)(enc + (size_t)b * NC * L3);
        float s = 0.f;
        for (int j = tid; j < (NC * L3) / 4; j += 256) {
            float4 v = e4[j];
            int f = j * 4;
            s += v.x * c1_w[(f + 0) / L3] * f1_w[(f + 0) % L3];
            s += v.y * c1_w[(f + 1) / L3] * f1_w[(f + 1) % L3];
            s += v.z * c1_w[(f + 2) / L3] * f1_w[(f + 2) % L3];
            s += v.w * c1_w[(f + 3) / L3] * f1_w[(f + 3) % L3];
        }
        for (int off = 32; off > 0; off >>= 1) s += __shfl_down(s, off, 64);
        int lane = tid & 63, wid = tid >> 6;
        if (lane == 0) red[wid] = s;
        __syncthreads();
        if (tid == 0) {
            float tot = red[0] + red[1] + red[2] + red[3];
            float fwsum = 0.f;
            for (int v = 0; v < L3; ++v) fwsum += f1_w[v];
            float x = tot + c1_b[0] * fwsum + f1_b[0];
            alpha[b] = 1.f / (1.f + expf(-x));   // ALPHA_M = 1
        }
        return;
    }

    // -------- blur path (648 blocks) --------
    int blk = blockIdx.x;
    int c = blk / BNTILE;
    int t = blk % BNTILE;
    int tz = t / (BNT * BNT), ty = (t / BNT) % BNT, tx = t % BNT;
    int bz = tz * BTS, by = ty * BTS, bx = tx * BTS;
    const float* ib = in + (size_t)c * VOX;

    // phase 1: x-pass straight from global
    bool xedge = (bx == 0) || (bx == DD - BTS);
    for (int i = tid; i < BHY * BHZ * BTS; i += 256) {
        int hy = i / (BHZ * BTS);
        int r2 = i - hy * (BHZ * BTS);
        int hz = r2 >> 4;
        int xo = r2 & 15;
        int gz = bz + hz - 3, gy = by + hy - 3;
        float s = 0.f;
        if ((unsigned)gz < DD && (unsigned)gy < DD) {
            const float* p = ib + (gz * DD + gy) * DD + (bx + xo - 3);
            if (!xedge) {
                #pragma unroll
                for (int dx = 0; dx < 7; ++dx) s += p[dx];
            } else {
                int gx0 = bx + xo - 3;
                #pragma unroll
                for (int dx = 0; dx < 7; ++dx)
                    if ((unsigned)(gx0 + dx) < DD) s += p[dx];
            }
        }
        xs[(hy * 23 + hz) * 16 + xo] = s;
    }
    __syncthreads();

    // phase 2: y-pass IN PLACE (running sum per (hz,xo) column)
    for (int cc = tid; cc < BHZ * BTS; cc += 256) {
        int hz = cc >> 4, xo = cc & 15;
        int base = hz * 16 + xo;
        float s = 0.f;
        #pragma unroll
        for (int hy = 0; hy < 7; ++hy) s += xs[hy * 368 + base];
        #pragma unroll
        for (int yo = 0; yo < 16; ++yo) {
            float old = xs[yo * 368 + base];
            float nxt = (yo < 15) ? xs[(yo + 7) * 368 + base] : 0.f;
            xs[yo * 368 + base] = s;          // overwrite: ysum[yo]
            s += nxt - old;
        }
    }
    __syncthreads();

    // phase 3: z-pass (running sum) + clip/scale + store
    {
        int yo = tid >> 4, xo = tid & 15;
        int base = yo * 368 + xo;
        float s = 0.f;
        #pragma unroll
        for (int hz = 0; hz < 7; ++hz) s += xs[base + hz * 16];
        float* ob = out + (size_t)c * VOX + (by + yo) * DD + bx + xo;
        #pragma unroll
        for (int zo = 0; zo < 16; ++zo) {
            float v = s * (1.0f / 343.0f);
            v = fminf(fmaxf(v, -0.01f), 0.01f) * 96.0f;
            ob[(size_t)(bz + zo) * DD * DD] = v;
            s += xs[base + (zo + 7) * 16] - xs[base + zo * 16];
        }
    }
}

// ---------------- direct-gather trilinear sampling (no LDS) ---------------
// orig+mask are L3-resident (56 MB) and tile working sets are L1/L2-warm;
// LDS staging was pure overhead. Taps read as contiguous float2 x-pairs.
// iz = min((int)cz, 94) keeps iz+1 in-bounds with correct lerp (fz hits 1.0
// exactly when cz==95), so no per-tap clamps are needed.
__global__ __launch_bounds__(256, 8) void sample_tile(
        const float* __restrict__ orig,
        const float* __restrict__ mask,
        const float* __restrict__ field,
        const float* __restrict__ alpha,
        float* __restrict__ out) {
    int blk = blockIdx.x;
    int b = blk / STILE;
    int r = blk % STILE;
    int o = r & 7;          // octant -> XCD (288 % 8 == 0)
    int l = r >> 3;         // 0..35 within octant
    int zh = o >> 2;        // z half  (4 z-tiles each)
    int yq = o & 3;         // y quarter (3 y-tiles each)
    int lz4 = l / 9, ly3 = (l / 3) % 3, lx3 = l % 3;
    int tz = zh * 4 + lz4;
    int ty = yq * 3 + ly3;
    int tx = lx3;
    int bz = tz * TZ, by = ty * TY, bx = tx * TX;

    const float* ob = orig + (size_t)b * VOX;
    const float* mb = mask + (size_t)b * VOX;
    int tid = threadIdx.x;
    float a = alpha[b];

    const vfloat4* fz4 = (const vfloat4*)field;
    const vfloat4* fy4 = (const vfloat4*)(field + VOX);
    const vfloat4* fx4 = (const vfloat4*)(field + 2 * VOX);
    vfloat4* oD = (vfloat4*)(out);
    vfloat4* oM = (vfloat4*)(out + (size_t)NB * VOX);

    int lz  = tid >> 6;          // 0..3  (z within slice quad)
    int ly  = (tid >> 3) & 7;    // 0..7
    int lxq = tid & 7;           // x-quad 0..7
    int gy  = by + ly;
    int gx0 = bx + 4 * lxq;
    float gyf = (float)gy;
    float gx0f = (float)gx0;

    auto samp = [&](float gzf, float dzv, float dyv, float dxv,
                    float gxf) -> vfloat2 {
        float cz = fminf(fmaxf(fmaf(a, dzv, gzf), 0.f), 95.f);
        float cy = fminf(fmaxf(fmaf(a, dyv, gyf), 0.f), 95.f);
        float cx = fminf(fmaxf(fmaf(a, dxv, gxf), 0.f), 95.f);
        int iz = min((int)cz, DD - 2);
        int iy = min((int)cy, DD - 2);
        int ix = min((int)cx, DD - 2);
        float fzf = cz - (float)iz;
        float fyf = cy - (float)iy;
        float fxf = cx - (float)ix;
        int t = iz * (DD * DD) + iy * DD + ix;

        f2u o00 = *(const f2u*)(ob + t);
        f2u o01 = *(const f2u*)(ob + t + DD);
        f2u o10 = *(const f2u*)(ob + t + DD * DD);
        f2u o11 = *(const f2u*)(ob + t + DD * DD + DD);
        f2u m00 = *(const f2u*)(mb + t);
        f2u m01 = *(const f2u*)(mb + t + DD);
        f2u m10 = *(const f2u*)(mb + t + DD * DD);
        f2u m11 = *(const f2u*)(mb + t + DD * DD + DD);

        float qx = 1.f - fxf, qy = 1.f - fyf, qz = 1.f - fzf;
        float c00 = o00.x * qx + o00.y * fxf;
        float c01 = o01.x * qx + o01.y * fxf;
        float c10 = o10.x * qx + o10.y * fxf;
        float c11 = o11.x * qx + o11.y * fxf;
        float d00 = m00.x * qx + m00.y * fxf;
        float d01 = m01.x * qx + m01.y * fxf;
        float d10 = m10.x * qx + m10.y * fxf;
        float d11 = m11.x * qx + m11.y * fxf;
        float c0 = c00 * qy + c01 * fyf;
        float c1 = c10 * qy + c11 * fyf;
        float d0 = d00 * qy + d01 * fyf;
        float d1 = d10 * qy + d11 * fyf;
        vfloat2 rv;
        rv.x = c0 * qz + c1 * fzf;
        rv.y = d0 * qz + d1 * fzf;
        return rv;
    };

    int vp4 = (((bz + lz) * DD + gy) * DD + gx0) >> 2;   // float4 index
    vfloat4 dz = fz4[vp4], dy = fy4[vp4], dx = fx4[vp4];
    size_t ob0 = (size_t)b * (VOX / 4);

    #pragma unroll
    for (int it = 0; it < TZ / 4; ++it) {
        vfloat4 dzn = {0,0,0,0}, dyn = {0,0,0,0}, dxn = {0,0,0,0};
        if (it < TZ / 4 - 1) {                 // prefetch next z-quad (static)
            int vq = vp4 + DD * DD;
            dzn = fz4[vq]; dyn = fy4[vq]; dxn = fx4[vq];
        }
        float gzf = (float)(bz + 4 * it + lz);

        vfloat2 r0 = samp(gzf, dz.x, dy.x, dx.x, gx0f);
        vfloat2 r1 = samp(gzf, dz.y, dy.y, dx.y, gx0f + 1.f);
        vfloat2 r2 = samp(gzf, dz.z, dy.z, dx.z, gx0f + 2.f);
        vfloat2 r3 = samp(gzf, dz.w, dy.w, dx.w, gx0f + 3.f);

        vfloat4 vD = {r0.x, r1.x, r2.x, r3.x};
        vfloat4 vM = {r0.y, r1.y, r2.y, r3.y};
        __builtin_nontemporal_store(vD, &oD[ob0 + vp4]);
        __builtin_nontemporal_store(vM, &oM[ob0 + vp4]);

        vp4 += DD * DD;
        dz = dzn; dy = dyn; dx = dxn;
    }
}

extern "C" void kernel_launch(void* const* d_in, const int* in_sizes, int n_in,
                              void* d_out, int out_size, void* d_ws, size_t ws_size,
                              hipStream_t stream) {
    const float* enc   = (const float*)d_in[0];
    const float* orig  = (const float*)d_in[1];
    const float* mask  = (const float*)d_in[2];
    const float* c1_w  = (const float*)d_in[3];
    const float* c1_b  = (const float*)d_in[4];
    const float* f1_w  = (const float*)d_in[5];
    const float* f1_b  = (const float*)d_in[6];
    const float* offs  = (const float*)d_in[7];
    float* out = (float*)d_out;

    float* ws = (float*)d_ws;
    float* alpha = ws;                 // 8 floats
    float* fieldB = ws + 16;           // 3*VOX floats (final blurred field)

    blur_alpha<<<3 * BNTILE + NB, 256, 0, stream>>>(
        offs, fieldB, enc, c1_w, c1_b, f1_w, f1_b, alpha);
    sample_tile<<<NB * STILE, 256, 0, stream>>>(orig, mask, fieldB, alpha, out);
}

// Round 8
// 169.410 us; speedup vs baseline: 1.1969x; 1.1969x over previous
//
// decoder_ds — R7 resubmission (identical R5 logic; third infra retry).
#include <hip/hip_runtime.h>
#include <hip/hip_fp16.h>
#include <math.h>

#define DD 96
#define VOX (96*96*96)
#define NB 8
#define NC 128
#define L3 125

// ---- blur tiling: 16^3 output tile, x->y->z in-place passes ----
#define BTS 16
#define BNT 6
#define BNTILE (BNT*BNT*BNT)   // 216
#define BHZ 22                 // z halo extent
#define BHY 22                 // y halo extent
// LDS layout: xs[(hy*23 + hz)*16 + xo]  (hz stride padded 22->23)
#define XSN (BHY * 23 * BTS)   // 8096 floats = 32.4 KB

// ---- sample tiling: (z,y,x) = (12,8,32), x-quads, 4 z-slices/iter ----
#define TZ 12
#define TY 8
#define TX 32
#define NTZ 8                  // 96/12
#define NTY 12                 // 96/8
#define NTX 3
#define STILE (NTZ*NTY*NTX)    // 288 (divisible by 8 -> XCD octants)
#define HZS 14                 // TZ+2
#define HYS 10                 // TY+2
#define HXS 34                 // TX+2
#define HXP 35                 // padded (odd) row stride
#define HN (HZS*HYS*HXS)       // 4760 elements staged
#define HLDS (HZS*HYS*HXP)     // 4900 slots = 19600 B

typedef float vfloat2 __attribute__((ext_vector_type(2)));
typedef float vfloat4 __attribute__((ext_vector_type(4)));

static __device__ __forceinline__ vfloat2 h2f(__half2 h) {
    float2 t = __half22float2(h);
    vfloat2 r; r.x = t.x; r.y = t.y;
    return r;
}

// ---------------- 7^3 box blur (x->y->z, in-place LDS) + alpha tail -------
// Phase 1: one thread per (hy,hz) row, 7 aligned float4 loads (28-float
// window covers the 22-tap row at any 16B-aligned base), running x-sum in
// registers. ~16x fewer VMEM issues than 7-scalar-loads-per-output.
__global__ __launch_bounds__(256) void blur_alpha(
        const float* __restrict__ in, float* __restrict__ out,
        const float* __restrict__ enc,
        const float* __restrict__ c1_w, const float* __restrict__ c1_b,
        const float* __restrict__ f1_w, const float* __restrict__ f1_b,
        float* __restrict__ alpha) {
    __shared__ float xs[XSN];
    __shared__ float red[4];
    int tid = threadIdx.x;

    if (blockIdx.x >= 3 * BNTILE) {
        // -------- alpha path (8 blocks) --------
        int b = blockIdx.x - 3 * BNTILE;
        const float4* e4 = (const float4*)(enc + (size_t)b * NC * L3);
        float s = 0.f;
        for (int j = tid; j < (NC * L3) / 4; j += 256) {
            float4 v = e4[j];
            int f = j * 4;
            s += v.x * c1_w[(f + 0) / L3] * f1_w[(f + 0) % L3];
            s += v.y * c1_w[(f + 1) / L3] * f1_w[(f + 1) % L3];
            s += v.z * c1_w[(f + 2) / L3] * f1_w[(f + 2) % L3];
            s += v.w * c1_w[(f + 3) / L3] * f1_w[(f + 3) % L3];
        }
        for (int off = 32; off > 0; off >>= 1) s += __shfl_down(s, off, 64);
        int lane = tid & 63, wid = tid >> 6;
        if (lane == 0) red[wid] = s;
        __syncthreads();
        if (tid == 0) {
            float tot = red[0] + red[1] + red[2] + red[3];
            float fwsum = 0.f;
            for (int v = 0; v < L3; ++v) fwsum += f1_w[v];
            float x = tot + c1_b[0] * fwsum + f1_b[0];
            alpha[b] = 1.f / (1.f + expf(-x));   // ALPHA_M = 1
        }
        return;
    }

    // -------- blur path (648 blocks) --------
    int blk = blockIdx.x;
    int c = blk / BNTILE;
    int t = blk % BNTILE;
    int tz = t / (BNT * BNT), ty = (t / BNT) % BNT, tx = t % BNT;
    int bz = tz * BTS, by = ty * BTS, bx = tx * BTS;
    const float* ib = in + (size_t)c * VOX;

    // phase 1: x-pass, one thread per (hy,hz) row
    for (int rr = tid; rr < BHY * BHZ; rr += 256) {
        int hy = rr / BHZ, hz = rr - (rr / BHZ) * BHZ;
        int gz = bz + hz - 3, gy = by + hy - 3;
        float* xrow = &xs[(hy * 23 + hz) * 16];
        if ((unsigned)gz >= DD || (unsigned)gy >= DD) {
            #pragma unroll
            for (int xo = 0; xo < 16; ++xo) xrow[xo] = 0.f;
            continue;
        }
        const float* rp = ib + (gz * DD + gy) * DD;
        int base = bx - 4;
        if (base < 0) base = 0;
        if (base > DD - 28) base = DD - 28;
        const float4* p4 = (const float4*)(rp + base);
        float w[28];
        #pragma unroll
        for (int q = 0; q < 7; ++q) {
            float4 t4 = p4[q];
            w[q * 4 + 0] = t4.x; w[q * 4 + 1] = t4.y;
            w[q * 4 + 2] = t4.z; w[q * 4 + 3] = t4.w;
        }
        // v[j] = in[gx = bx-3+j], zero outside [0,96)
        float v[22];
        if (bx == 0) {                       // base=0, shift=-3
            v[0] = v[1] = v[2] = 0.f;
            #pragma unroll
            for (int j = 3; j < 22; ++j) v[j] = w[j - 3];
        } else if (bx == DD - BTS) {         // base=68, shift=+9
            #pragma unroll
            for (int j = 0; j < 19; ++j) v[j] = w[j + 9];
            v[19] = v[20] = v[21] = 0.f;
        } else {                             // base=bx-4, shift=+1
            #pragma unroll
            for (int j = 0; j < 22; ++j) v[j] = w[j + 1];
        }
        float s = v[0] + v[1] + v[2] + v[3] + v[4] + v[5] + v[6];
        xrow[0] = s;
        #pragma unroll
        for (int xo = 1; xo < 16; ++xo) {
            s += v[xo + 6] - v[xo - 1];
            xrow[xo] = s;
        }
    }
    __syncthreads();

    // phase 2: y-pass IN PLACE (running sum per (hz,xo) column)
    for (int cc = tid; cc < BHZ * BTS; cc += 256) {
        int hz = cc >> 4, xo = cc & 15;
        int base = hz * 16 + xo;
        float s = 0.f;
        #pragma unroll
        for (int hy = 0; hy < 7; ++hy) s += xs[hy * 368 + base];
        #pragma unroll
        for (int yo = 0; yo < 16; ++yo) {
            float old = xs[yo * 368 + base];
            float nxt = (yo < 15) ? xs[(yo + 7) * 368 + base] : 0.f;
            xs[yo * 368 + base] = s;          // overwrite: ysum[yo]
            s += nxt - old;
        }
    }
    __syncthreads();

    // phase 3: z-pass (running sum) + clip/scale + store
    {
        int yo = tid >> 4, xo = tid & 15;
        int base = yo * 368 + xo;
        float s = 0.f;
        #pragma unroll
        for (int hz = 0; hz < 7; ++hz) s += xs[base + hz * 16];
        float* ob = out + (size_t)c * VOX + (by + yo) * DD + bx + xo;
        #pragma unroll
        for (int zo = 0; zo < 16; ++zo) {
            float v = s * (1.0f / 343.0f);
            v = fminf(fmaxf(v, -0.01f), 0.01f) * 96.0f;
            ob[(size_t)(bz + zo) * DD * DD] = v;
            s += xs[base + (zo + 7) * 16] - xs[base + zo * 16];
        }
    }
}

// ---------------- tiled trilinear sampling, (12,8,32) tile, x-quads -------
// (R3 structure — LDS-staged gather; direct-gather variant regressed
// 48->76 us because scattered 8B global loads are VMEM-issue-bound.)
// Invariant: |disp| = |alpha*field*96| <= 0.96 < 1 voxel, and the halo
// replicates clamped edges, so the +1 tap in each dim is ALWAYS the adjacent
// LDS slot (no x1/y1/z1 clamps needed).
__global__ __launch_bounds__(256, 8) void sample_tile(
        const float* __restrict__ orig,
        const float* __restrict__ mask,
        const float* __restrict__ field,
        const float* __restrict__ alpha,
        float* __restrict__ out) {
    __shared__ __half2 tile[HLDS];

    int blk = blockIdx.x;
    int b = blk / STILE;
    int r = blk % STILE;
    int o = r & 7;          // octant -> XCD (288 % 8 == 0)
    int l = r >> 3;         // 0..35 within octant
    int zh = o >> 2;        // z half  (4 z-tiles each)
    int yq = o & 3;         // y quarter (3 y-tiles each)
    int lz4 = l / 9, ly3 = (l / 3) % 3, lx3 = l % 3;
    int tz = zh * 4 + lz4;
    int ty = yq * 3 + ly3;
    int tx = lx3;
    int bz = tz * TZ, by = ty * TY, bx = tx * TX;

    const float* ob = orig + (size_t)b * VOX;
    const float* mb = mask + (size_t)b * VOX;
    int tid = threadIdx.x;

    // stage (orig,mask) halo as half2
    for (int i = tid; i < HN; i += 256) {
        int hz = i / (HYS * HXS);
        int rr = i - hz * (HYS * HXS);
        int hy = rr / HXS;
        int hx = rr - hy * HXS;
        int gz = min(max(bz + hz - 1, 0), DD - 1);
        int gy = min(max(by + hy - 1, 0), DD - 1);
        int gx = min(max(bx + hx - 1, 0), DD - 1);
        int g = (gz * DD + gy) * DD + gx;
        tile[(hz * HYS + hy) * HXP + hx] = __floats2half2_rn(ob[g], mb[g]);
    }
    float a = alpha[b];
    __syncthreads();

    const vfloat4* fz4 = (const vfloat4*)field;
    const vfloat4* fy4 = (const vfloat4*)(field + VOX);
    const vfloat4* fx4 = (const vfloat4*)(field + 2 * VOX);
    vfloat4* oD = (vfloat4*)(out);
    vfloat4* oM = (vfloat4*)(out + (size_t)NB * VOX);

    int lz  = tid >> 6;          // 0..3  (z within slice quad)
    int ly  = (tid >> 3) & 7;    // 0..7
    int lxq = tid & 7;           // x-quad 0..7
    int gy  = by + ly;
    int gx0 = bx + 4 * lxq;
    float gyf = (float)gy;
    float gx0f = (float)gx0;
    float c1z = (float)(1 - bz), c1y = (float)(1 - by), c1x = (float)(1 - bx);

    auto samp = [&](float gzf, float dzv, float dyv, float dxv,
                    float gxf) -> vfloat2 {
        float cz = fminf(fmaxf(fmaf(a, dzv, gzf), 0.f), (float)(DD - 1)) + c1z;
        float cy = fminf(fmaxf(fmaf(a, dyv, gyf), 0.f), (float)(DD - 1)) + c1y;
        float cx = fminf(fmaxf(fmaf(a, dxv, gxf), 0.f), (float)(DD - 1)) + c1x;
        float flz = floorf(cz), fly = floorf(cy), flx = floorf(cx);
        float fzf = cz - flz, fyf = cy - fly, fxf = cx - flx;
        int iz = (int)flz, iy = (int)fly, ix = (int)flx;

        const __half2* tp = tile + (iz * HYS + iy) * HXP + ix;
        vfloat2 v000 = h2f(tp[0]);
        vfloat2 v001 = h2f(tp[1]);
        vfloat2 v010 = h2f(tp[HXP]);
        vfloat2 v011 = h2f(tp[HXP + 1]);
        vfloat2 v100 = h2f(tp[HYS * HXP]);
        vfloat2 v101 = h2f(tp[HYS * HXP + 1]);
        vfloat2 v110 = h2f(tp[(HYS + 1) * HXP]);
        vfloat2 v111 = h2f(tp[(HYS + 1) * HXP + 1]);

        vfloat2 FX = {fxf, fxf}, FY = {fyf, fyf}, FZ = {fzf, fzf};
        vfloat2 c00 = v000 + FX * (v001 - v000);
        vfloat2 c01 = v010 + FX * (v011 - v010);
        vfloat2 c10 = v100 + FX * (v101 - v100);
        vfloat2 c11 = v110 + FX * (v111 - v110);
        vfloat2 c0 = c00 + FY * (c01 - c00);
        vfloat2 c1 = c10 + FY * (c11 - c10);
        return c0 + FZ * (c1 - c0);
    };

    int vp4 = (((bz + lz) * DD + gy) * DD + gx0) >> 2;   // float4 index
    vfloat4 dz = fz4[vp4], dy = fy4[vp4], dx = fx4[vp4];
    size_t ob0 = (size_t)b * (VOX / 4);

    #pragma unroll
    for (int it = 0; it < TZ / 4; ++it) {
        vfloat4 dzn = {0,0,0,0}, dyn = {0,0,0,0}, dxn = {0,0,0,0};
        if (it < TZ / 4 - 1) {                 // prefetch next z-quad (static)
            int vq = vp4 + DD * DD;
            dzn = fz4[vq]; dyn = fy4[vq]; dxn = fx4[vq];
        }
        float gzf = (float)(bz + 4 * it + lz);

        vfloat2 r0 = samp(gzf, dz.x, dy.x, dx.x, gx0f);
        vfloat2 r1 = samp(gzf, dz.y, dy.y, dx.y, gx0f + 1.f);
        vfloat2 r2 = samp(gzf, dz.z, dy.z, dx.z, gx0f + 2.f);
        vfloat2 r3 = samp(gzf, dz.w, dy.w, dx.w, gx0f + 3.f);

        vfloat4 vD = {r0.x, r1.x, r2.x, r3.x};
        vfloat4 vM = {r0.y, r1.y, r2.y, r3.y};
        __builtin_nontemporal_store(vD, &oD[ob0 + vp4]);
        __builtin_nontemporal_store(vM, &oM[ob0 + vp4]);

        vp4 += DD * DD;
        dz = dzn; dy = dyn; dx = dxn;
    }
}

extern "C" void kernel_launch(void* const* d_in, const int* in_sizes, int n_in,
                              void* d_out, int out_size, void* d_ws, size_t ws_size,
                              hipStream_t stream) {
    const float* enc   = (const float*)d_in[0];
    const float* orig  = (const float*)d_in[1];
    const float* mask  = (const float*)d_in[2];
    const float* c1_w  = (const float*)d_in[3];
    const float* c1_b  = (const float*)d_in[4];
    const float* f1_w  = (const float*)d_in[5];
    const float* f1_b  = (const float*)d_in[6];
    const float* offs  = (const float*)d_in[7];
    float* out = (float*)d_out;

    float* ws = (float*)d_ws;
    float* alpha = ws;                 // 8 floats
    float* fieldB = ws + 16;           // 3*VOX floats (final blurred field)

    blur_alpha<<<3 * BNTILE + NB, 256, 0, stream>>>(
        offs, fieldB, enc, c1_w, c1_b, f1_w, f1_b, alpha);
    sample_tile<<<NB * STILE, 256, 0, stream>>>(orig, mask, fieldB, alpha, out);
}

// Round 9
// 163.884 us; speedup vs baseline: 1.2372x; 1.0337x over previous
//
// decoder_ds — R9: blur z-split (8x16x16 tiles, 1296 blocks, 2x occupancy).
#include <hip/hip_runtime.h>
#include <hip/hip_fp16.h>
#include <math.h>

#define DD 96
#define VOX (96*96*96)
#define NB 8
#define NC 128
#define L3 125

// ---- blur tiling: 8x16x16 output tile, x->y->z in-place passes ----
#define BTZ 8                  // z output extent
#define BTS 16                 // y/x output extent
#define NBZ 12                 // 96/8
#define NBY 6
#define NBX 6
#define BNTILE (NBZ*NBY*NBX)   // 432 per component
#define BHZ 14                 // z halo extent (8+6)
#define BHY 22                 // y halo extent (16+6)
// LDS layout: xs[hy*225 + hz*16 + xo]; 225 % 32 == 1 -> y-pass column reads
// (stride 225) walk banks, conflict-free. Size 22*225 = 4950 floats = 19.8 KB.
#define XROW 225
#define XSN (BHY * XROW)

// ---- sample tiling: (z,y,x) = (12,8,32), x-quads, 4 z-slices/iter ----
#define TZ 12
#define TY 8
#define TX 32
#define NTZ 8                  // 96/12
#define NTY 12                 // 96/8
#define NTX 3
#define STILE (NTZ*NTY*NTX)    // 288 (divisible by 8 -> XCD octants)
#define HZS 14                 // TZ+2
#define HYS 10                 // TY+2
#define HXS 34                 // TX+2
#define HXP 35                 // padded (odd) row stride
#define HN (HZS*HYS*HXS)       // 4760 elements staged
#define HLDS (HZS*HYS*HXP)     // 4900 slots = 19600 B

typedef float vfloat2 __attribute__((ext_vector_type(2)));
typedef float vfloat4 __attribute__((ext_vector_type(4)));

static __device__ __forceinline__ vfloat2 h2f(__half2 h) {
    float2 t = __half22float2(h);
    vfloat2 r; r.x = t.x; r.y = t.y;
    return r;
}

// ---------------- 7^3 box blur (x->y->z, in-place LDS) + alpha tail -------
// Phase 1: one thread per (hy,hz) row, 7 aligned float4 loads (28-float
// window covers the 22-tap row at any 16B-aligned base), running x-sum in
// registers.
__global__ __launch_bounds__(256) void blur_alpha(
        const float* __restrict__ in, float* __restrict__ out,
        const float* __restrict__ enc,
        const float* __restrict__ c1_w, const float* __restrict__ c1_b,
        const float* __restrict__ f1_w, const float* __restrict__ f1_b,
        float* __restrict__ alpha) {
    __shared__ float xs[XSN];
    __shared__ float red[4];
    int tid = threadIdx.x;

    if (blockIdx.x >= 3 * BNTILE) {
        // -------- alpha path (8 blocks) --------
        int b = blockIdx.x - 3 * BNTILE;
        const float4* e4 = (const float4*)(enc + (size_t)b * NC * L3);
        float s = 0.f;
        for (int j = tid; j < (NC * L3) / 4; j += 256) {
            float4 v = e4[j];
            int f = j * 4;
            s += v.x * c1_w[(f + 0) / L3] * f1_w[(f + 0) % L3];
            s += v.y * c1_w[(f + 1) / L3] * f1_w[(f + 1) % L3];
            s += v.z * c1_w[(f + 2) / L3] * f1_w[(f + 2) % L3];
            s += v.w * c1_w[(f + 3) / L3] * f1_w[(f + 3) % L3];
        }
        for (int off = 32; off > 0; off >>= 1) s += __shfl_down(s, off, 64);
        int lane = tid & 63, wid = tid >> 6;
        if (lane == 0) red[wid] = s;
        __syncthreads();
        if (tid == 0) {
            float tot = red[0] + red[1] + red[2] + red[3];
            float fwsum = 0.f;
            for (int v = 0; v < L3; ++v) fwsum += f1_w[v];
            float x = tot + c1_b[0] * fwsum + f1_b[0];
            alpha[b] = 1.f / (1.f + expf(-x));   // ALPHA_M = 1
        }
        return;
    }

    // -------- blur path (1296 blocks, ~5 blocks/CU @ 19.8 KB LDS) --------
    int blk = blockIdx.x;
    int c = blk / BNTILE;
    int t = blk % BNTILE;
    int tz = t / (NBY * NBX), ty = (t / NBX) % NBY, tx = t % NBX;
    int bz = tz * BTZ, by = ty * BTS, bx = tx * BTS;
    const float* ib = in + (size_t)c * VOX;

    // phase 1: x-pass, one thread per (hy,hz) row  (308 rows)
    for (int rr = tid; rr < BHY * BHZ; rr += 256) {
        int hy = rr / BHZ, hz = rr - (rr / BHZ) * BHZ;
        int gz = bz + hz - 3, gy = by + hy - 3;
        float* xrow = &xs[hy * XROW + hz * 16];
        if ((unsigned)gz >= DD || (unsigned)gy >= DD) {
            #pragma unroll
            for (int xo = 0; xo < 16; ++xo) xrow[xo] = 0.f;
            continue;
        }
        const float* rp = ib + (gz * DD + gy) * DD;
        int base = bx - 4;
        if (base < 0) base = 0;
        if (base > DD - 28) base = DD - 28;
        const float4* p4 = (const float4*)(rp + base);
        float w[28];
        #pragma unroll
        for (int q = 0; q < 7; ++q) {
            float4 t4 = p4[q];
            w[q * 4 + 0] = t4.x; w[q * 4 + 1] = t4.y;
            w[q * 4 + 2] = t4.z; w[q * 4 + 3] = t4.w;
        }
        // v[j] = in[gx = bx-3+j], zero outside [0,96)
        float v[22];
        if (bx == 0) {                       // base=0, shift=-3
            v[0] = v[1] = v[2] = 0.f;
            #pragma unroll
            for (int j = 3; j < 22; ++j) v[j] = w[j - 3];
        } else if (bx == DD - BTS) {         // base=68, shift=+9
            #pragma unroll
            for (int j = 0; j < 19; ++j) v[j] = w[j + 9];
            v[19] = v[20] = v[21] = 0.f;
        } else {                             // base=bx-4, shift=+1
            #pragma unroll
            for (int j = 0; j < 22; ++j) v[j] = w[j + 1];
        }
        float s = v[0] + v[1] + v[2] + v[3] + v[4] + v[5] + v[6];
        xrow[0] = s;
        #pragma unroll
        for (int xo = 1; xo < 16; ++xo) {
            s += v[xo + 6] - v[xo - 1];
            xrow[xo] = s;
        }
    }
    __syncthreads();

    // phase 2: y-pass IN PLACE (running sum per (hz,xo) column, 224 cols)
    if (tid < BHZ * BTS) {
        int hz = tid >> 4, xo = tid & 15;
        int base = hz * 16 + xo;
        float s = 0.f;
        #pragma unroll
        for (int hy = 0; hy < 7; ++hy) s += xs[hy * XROW + base];
        #pragma unroll
        for (int yo = 0; yo < 16; ++yo) {
            float old = xs[yo * XROW + base];
            float nxt = (yo < 15) ? xs[(yo + 7) * XROW + base] : 0.f;
            xs[yo * XROW + base] = s;          // overwrite: ysum[yo]
            s += nxt - old;
        }
    }
    __syncthreads();

    // phase 3: z-pass (running sum) + clip/scale + store (256 threads)
    {
        int yo = tid >> 4, xo = tid & 15;
        int base = yo * XROW + xo;
        float s = 0.f;
        #pragma unroll
        for (int hz = 0; hz < 7; ++hz) s += xs[base + hz * 16];
        float* ob = out + (size_t)c * VOX + (by + yo) * DD + bx + xo;
        #pragma unroll
        for (int zo = 0; zo < BTZ; ++zo) {
            float v = s * (1.0f / 343.0f);
            v = fminf(fmaxf(v, -0.01f), 0.01f) * 96.0f;
            ob[(size_t)(bz + zo) * DD * DD] = v;
            s += xs[base + (zo + 7) * 16] - xs[base + zo * 16];
        }
    }
}

// ---------------- tiled trilinear sampling, (12,8,32) tile, x-quads -------
// (R3 structure — LDS-staged gather; direct-gather variant regressed
// 48->76 us because scattered 8B global loads are VMEM-issue-bound.)
// Invariant: |disp| = |alpha*field*96| <= 0.96 < 1 voxel, and the halo
// replicates clamped edges, so the +1 tap in each dim is ALWAYS the adjacent
// LDS slot (no x1/y1/z1 clamps needed).
__global__ __launch_bounds__(256, 8) void sample_tile(
        const float* __restrict__ orig,
        const float* __restrict__ mask,
        const float* __restrict__ field,
        const float* __restrict__ alpha,
        float* __restrict__ out) {
    __shared__ __half2 tile[HLDS];

    int blk = blockIdx.x;
    int b = blk / STILE;
    int r = blk % STILE;
    int o = r & 7;          // octant -> XCD (288 % 8 == 0)
    int l = r >> 3;         // 0..35 within octant
    int zh = o >> 2;        // z half  (4 z-tiles each)
    int yq = o & 3;         // y quarter (3 y-tiles each)
    int lz4 = l / 9, ly3 = (l / 3) % 3, lx3 = l % 3;
    int tz = zh * 4 + lz4;
    int ty = yq * 3 + ly3;
    int tx = lx3;
    int bz = tz * TZ, by = ty * TY, bx = tx * TX;

    const float* ob = orig + (size_t)b * VOX;
    const float* mb = mask + (size_t)b * VOX;
    int tid = threadIdx.x;

    // stage (orig,mask) halo as half2
    for (int i = tid; i < HN; i += 256) {
        int hz = i / (HYS * HXS);
        int rr = i - hz * (HYS * HXS);
        int hy = rr / HXS;
        int hx = rr - hy * HXS;
        int gz = min(max(bz + hz - 1, 0), DD - 1);
        int gy = min(max(by + hy - 1, 0), DD - 1);
        int gx = min(max(bx + hx - 1, 0), DD - 1);
        int g = (gz * DD + gy) * DD + gx;
        tile[(hz * HYS + hy) * HXP + hx] = __floats2half2_rn(ob[g], mb[g]);
    }
    float a = alpha[b];
    __syncthreads();

    const vfloat4* fz4 = (const vfloat4*)field;
    const vfloat4* fy4 = (const vfloat4*)(field + VOX);
    const vfloat4* fx4 = (const vfloat4*)(field + 2 * VOX);
    vfloat4* oD = (vfloat4*)(out);
    vfloat4* oM = (vfloat4*)(out + (size_t)NB * VOX);

    int lz  = tid >> 6;          // 0..3  (z within slice quad)
    int ly  = (tid >> 3) & 7;    // 0..7
    int lxq = tid & 7;           // x-quad 0..7
    int gy  = by + ly;
    int gx0 = bx + 4 * lxq;
    float gyf = (float)gy;
    float gx0f = (float)gx0;
    float c1z = (float)(1 - bz), c1y = (float)(1 - by), c1x = (float)(1 - bx);

    auto samp = [&](float gzf, float dzv, float dyv, float dxv,
                    float gxf) -> vfloat2 {
        float cz = fminf(fmaxf(fmaf(a, dzv, gzf), 0.f), (float)(DD - 1)) + c1z;
        float cy = fminf(fmaxf(fmaf(a, dyv, gyf), 0.f), (float)(DD - 1)) + c1y;
        float cx = fminf(fmaxf(fmaf(a, dxv, gxf), 0.f), (float)(DD - 1)) + c1x;
        float flz = floorf(cz), fly = floorf(cy), flx = floorf(cx);
        float fzf = cz - flz, fyf = cy - fly, fxf = cx - flx;
        int iz = (int)flz, iy = (int)fly, ix = (int)flx;

        const __half2* tp = tile + (iz * HYS + iy) * HXP + ix;
        vfloat2 v000 = h2f(tp[0]);
        vfloat2 v001 = h2f(tp[1]);
        vfloat2 v010 = h2f(tp[HXP]);
        vfloat2 v011 = h2f(tp[HXP + 1]);
        vfloat2 v100 = h2f(tp[HYS * HXP]);
        vfloat2 v101 = h2f(tp[HYS * HXP + 1]);
        vfloat2 v110 = h2f(tp[(HYS + 1) * HXP]);
        vfloat2 v111 = h2f(tp[(HYS + 1) * HXP + 1]);

        vfloat2 FX = {fxf, fxf}, FY = {fyf, fyf}, FZ = {fzf, fzf};
        vfloat2 c00 = v000 + FX * (v001 - v000);
        vfloat2 c01 = v010 + FX * (v011 - v010);
        vfloat2 c10 = v100 + FX * (v101 - v100);
        vfloat2 c11 = v110 + FX * (v111 - v110);
        vfloat2 c0 = c00 + FY * (c01 - c00);
        vfloat2 c1 = c10 + FY * (c11 - c10);
        return c0 + FZ * (c1 - c0);
    };

    int vp4 = (((bz + lz) * DD + gy) * DD + gx0) >> 2;   // float4 index
    vfloat4 dz = fz4[vp4], dy = fy4[vp4], dx = fx4[vp4];
    size_t ob0 = (size_t)b * (VOX / 4);

    #pragma unroll
    for (int it = 0; it < TZ / 4; ++it) {
        vfloat4 dzn = {0,0,0,0}, dyn = {0,0,0,0}, dxn = {0,0,0,0};
        if (it < TZ / 4 - 1) {                 // prefetch next z-quad (static)
            int vq = vp4 + DD * DD;
            dzn = fz4[vq]; dyn = fy4[vq]; dxn = fx4[vq];
        }
        float gzf = (float)(bz + 4 * it + lz);

        vfloat2 r0 = samp(gzf, dz.x, dy.x, dx.x, gx0f);
        vfloat2 r1 = samp(gzf, dz.y, dy.y, dx.y, gx0f + 1.f);
        vfloat2 r2 = samp(gzf, dz.z, dy.z, dx.z, gx0f + 2.f);
        vfloat2 r3 = samp(gzf, dz.w, dy.w, dx.w, gx0f + 3.f);

        vfloat4 vD = {r0.x, r1.x, r2.x, r3.x};
        vfloat4 vM = {r0.y, r1.y, r2.y, r3.y};
        __builtin_nontemporal_store(vD, &oD[ob0 + vp4]);
        __builtin_nontemporal_store(vM, &oM[ob0 + vp4]);

        vp4 += DD * DD;
        dz = dzn; dy = dyn; dx = dxn;
    }
}

extern "C" void kernel_launch(void* const* d_in, const int* in_sizes, int n_in,
                              void* d_out, int out_size, void* d_ws, size_t ws_size,
                              hipStream_t stream) {
    const float* enc   = (const float*)d_in[0];
    const float* orig  = (const float*)d_in[1];
    const float* mask  = (const float*)d_in[2];
    const float* c1_w  = (const float*)d_in[3];
    const float* c1_b  = (const float*)d_in[4];
    const float* f1_w  = (const float*)d_in[5];
    const float* f1_b  = (const float*)d_in[6];
    const float* offs  = (const float*)d_in[7];
    float* out = (float*)d_out;

    float* ws = (float*)d_ws;
    float* alpha = ws;                 // 8 floats
    float* fieldB = ws + 16;           // 3*VOX floats (final blurred field)

    blur_alpha<<<3 * BNTILE + NB, 256, 0, stream>>>(
        offs, fieldB, enc, c1_w, c1_b, f1_w, f1_b, alpha);
    sample_tile<<<NB * STILE, 256, 0, stream>>>(orig, mask, fieldB, alpha, out);
}